// Round 6
// baseline (758.262 us; speedup 1.0000x reference)
//
#include <hip/hip_runtime.h>

#define NNODES 50000
#define NEDGES 800000
#define NF 96
#define NF4 24              // float4 per f32 row
#define CHUNK 64            // edges per tile
#define NB 16               // nodes per block (50000 / 16 = 3125 exactly)
#define THREADS 384         // 6 waves
#define BSTRIDE 104         // bf16 elems per Bt row (208 B, 16B-aligned)
#define ASTRIDE 97          // Acc row stride (floats) -> bank spread

typedef short bf16x8 __attribute__((ext_vector_type(8)));
typedef float f32x4 __attribute__((ext_vector_type(4)));

__device__ inline unsigned pk_bf16(float a, float b) {
    union { __bf16 h[2]; unsigned u; } q;
    q.h[0] = (__bf16)a; q.h[1] = (__bf16)b;
    return q.u;
}
__device__ inline unsigned short bf16_1(float a) {
    union { __bf16 h; unsigned short u; } q;
    q.h = (__bf16)a;
    return q.u;
}

// ---------------------------------------------------------------------------
// prep (3 blocks: We->bf16, W1^T, W2^T) + dst histogram (rest of grid)
// ---------------------------------------------------------------------------
__global__ __launch_bounds__(256) void prep_hist(
    const float* __restrict__ We, const float* __restrict__ W1,
    const float* __restrict__ W2, unsigned short* __restrict__ Wb,
    float* __restrict__ W1t, float* __restrict__ W2t,
    const int* __restrict__ ei, int* __restrict__ deg) {
    int b = blockIdx.x;
    if (b == 0) {
        for (int i = threadIdx.x; i < NF * NF; i += blockDim.x)
            Wb[i] = bf16_1(We[i]);
    } else if (b == 1) {
        for (int i = threadIdx.x; i < NF * NF; i += blockDim.x)
            W1t[(i % NF) * NF + i / NF] = W1[i];
    } else if (b == 2) {
        for (int i = threadIdx.x; i < NF * NF; i += blockDim.x)
            W2t[(i % NF) * NF + i / NF] = W2[i];
    } else {
        int e = (b - 3) * 256 + threadIdx.x;
        if (e < NEDGES) atomicAdd(&deg[ei[NEDGES + e]], 1);
    }
}

// ---------------------------------------------------------------------------
// 3-phase multi-block scan + slot fill (int atomics only)
// ---------------------------------------------------------------------------
#define SCAN_BLOCKS 196  // ceil(50000 / 256)

__global__ __launch_bounds__(256) void scan_partial(const int* __restrict__ deg,
                                                    int* __restrict__ bsum) {
    __shared__ int red[256];
    int t = threadIdx.x;
    int i = blockIdx.x * 256 + t;
    red[t] = (i < NNODES) ? deg[i] : 0;
    __syncthreads();
    for (int off = 128; off; off >>= 1) {
        if (t < off) red[t] += red[t + off];
        __syncthreads();
    }
    if (t == 0) bsum[blockIdx.x] = red[0];
}

__global__ __launch_bounds__(256) void scan_bsum(const int* __restrict__ bsum,
                                                 int* __restrict__ bstart) {
    __shared__ int s[256];
    int t = threadIdx.x;
    s[t] = (t < SCAN_BLOCKS) ? bsum[t] : 0;
    __syncthreads();
    for (int off = 1; off < 256; off <<= 1) {
        int v = (t >= off) ? s[t - off] : 0;
        __syncthreads();
        s[t] += v;
        __syncthreads();
    }
    bstart[t] = (t == 0) ? 0 : s[t - 1];  // exclusive
}

__global__ __launch_bounds__(256) void scan_write(const int* __restrict__ deg,
                                                  const int* __restrict__ bstart,
                                                  int* __restrict__ start,
                                                  int* __restrict__ cursor) {
    __shared__ int s[256];
    int t = threadIdx.x;
    int i = blockIdx.x * 256 + t;
    int d = (i < NNODES) ? deg[i] : 0;
    s[t] = d;
    __syncthreads();
    for (int off = 1; off < 256; off <<= 1) {
        int v = (t >= off) ? s[t - off] : 0;
        __syncthreads();
        s[t] += v;
        __syncthreads();
    }
    int excl = ((t == 0) ? 0 : s[t - 1]) + bstart[blockIdx.x];
    if (i < NNODES) {
        start[i] = excl;
        cursor[i] = excl;
        if (i == NNODES - 1) start[NNODES] = excl + d;
    }
}

__global__ void fill_kernel(const int* __restrict__ ei, int* __restrict__ cursor,
                            int* __restrict__ eidx, int* __restrict__ srcs) {
    int e = blockIdx.x * blockDim.x + threadIdx.x;
    if (e < NEDGES) {
        int p = atomicAdd(&cursor[ei[NEDGES + e]], 1);
        eidx[p] = e;
        srcs[p] = ei[e];
    }
}

// ---------------------------------------------------------------------------
// Fused edge-GEMM (bf16 MFMA) + LDS-atomic segment-sum, software-pipelined.
// Block owns NB=16 nodes (CSR range [s0,s1)). Per 64-edge chunk:
//   - ds_write Bt (bf16 attr tile) from prefetched regs; issue next eidx/srcs
//   - raw barrier (lgkmcnt only: global prefetches stay in flight)
//   - 12 MFMA; issue next chunk's attr rows
//   - epilogue: +x[src], ReLU, ds_add_f32 into Acc[node][feat]; raw barrier
// No M2 tile, no serial reduce, no float global atomics.
// ---------------------------------------------------------------------------
__global__ __launch_bounds__(THREADS, 4) void fused_edge_aggr(
    const float* __restrict__ attr, const int* __restrict__ eidx,
    const int* __restrict__ srcs_g, const int* __restrict__ start,
    const float* __restrict__ x, const unsigned short* __restrict__ Wb,
    const float* __restrict__ be, const float* __restrict__ epsp,
    float* __restrict__ h) {
    __shared__ short Bt[CHUNK][BSTRIDE];    // 13,312 B
    __shared__ float Acc[NB][ASTRIDE];      //  6,208 B
    __shared__ int sstart[NB + 1];

    const int t = threadIdx.x;
    const int n0 = blockIdx.x * NB;
    if (t <= NB) sstart[t] = start[n0 + t];
    for (int i = t; i < NB * ASTRIDE; i += THREADS) (&Acc[0][0])[i] = 0.f;
    __syncthreads();
    const int s0 = sstart[0], s1 = sstart[NB];

    const int lane = t & 63;
    const int w = t >> 6;             // wave id 0..5 (o-block)
    const int l15 = lane & 15;
    const int l4 = lane >> 4;         // 0..3
    const int rp0 = t / NF4;          // staging row base 0..15
    const int jp = t % NF4;           // staging float4 col
    const int w4l4 = w * 4 + l4;      // x float4 index for this lane's o's

    const float4* a4 = reinterpret_cast<const float4*>(attr);
    const float4* x4 = reinterpret_cast<const float4*>(x);

    // A-fragments: W rows for this wave's o-block (hoisted)
    bf16x8 af[3];
#pragma unroll
    for (int kb = 0; kb < 3; ++kb)
        af[kb] = *reinterpret_cast<const bf16x8*>(
            Wb + (16 * w + l15) * NF + kb * 32 + l4 * 8);

    const float4 bias4 = reinterpret_cast<const float4*>(be)[w4l4];
    f32x4 biasv = {bias4.x, bias4.y, bias4.z, bias4.w};

    if (s0 < s1) {
        // ---- prologue: prefetch chunk s0 ----
        int eV[4], sV[4];
#pragma unroll
        for (int p = 0; p < 4; ++p) {
            int sl = s0 + rp0 + 16 * p;
            eV[p] = eidx[sl < s1 ? sl : s1 - 1];
        }
#pragma unroll
        for (int et = 0; et < 4; ++et) {
            int sl = s0 + l15 + 16 * et;
            sV[et] = srcs_g[sl < s1 ? sl : s1 - 1];
        }
        float4 aV[4];
#pragma unroll
        for (int p = 0; p < 4; ++p) aV[p] = a4[(size_t)eV[p] * NF4 + jp];

        for (int cl = s0; cl < s1; cl += CHUNK) {
            const bool more = (cl + CHUNK) < s1;

            // ---- stage Bt from prefetched attr regs ----
#pragma unroll
            for (int p = 0; p < 4; ++p) {
                unsigned lo = pk_bf16(aV[p].x, aV[p].y);
                unsigned hi = pk_bf16(aV[p].z, aV[p].w);
                *reinterpret_cast<uint2*>(&Bt[rp0 + 16 * p][4 * jp]) =
                    make_uint2(lo, hi);
            }

            // ---- issue next chunk's indices + current chunk's x rows ----
            int eN[4], sN[4];
            if (more) {
#pragma unroll
                for (int p = 0; p < 4; ++p) {
                    int sl = cl + CHUNK + rp0 + 16 * p;
                    eN[p] = eidx[sl < s1 ? sl : s1 - 1];
                }
#pragma unroll
                for (int et = 0; et < 4; ++et) {
                    int sl = cl + CHUNK + l15 + 16 * et;
                    sN[et] = srcs_g[sl < s1 ? sl : s1 - 1];
                }
            }
            float4 xV[4];
#pragma unroll
            for (int et = 0; et < 4; ++et)
                xV[et] = x4[(size_t)sV[et] * NF4 + w4l4];

            // B1: Bt visible; global loads stay in flight (no vmcnt drain)
            asm volatile("s_waitcnt lgkmcnt(0)\n\ts_barrier" ::: "memory");

            // ---- MFMA: 4 edge-tiles x 3 K-steps ----
            f32x4 acc[4];
#pragma unroll
            for (int et = 0; et < 4; ++et) acc[et] = biasv;
#pragma unroll
            for (int et = 0; et < 4; ++et) {
#pragma unroll
                for (int kb = 0; kb < 3; ++kb) {
                    bf16x8 bf = *reinterpret_cast<const bf16x8*>(
                        &Bt[l15 + 16 * et][kb * 32 + l4 * 8]);
                    acc[et] = __builtin_amdgcn_mfma_f32_16x16x32_bf16(
                        af[kb], bf, acc[et], 0, 0, 0);
                }
            }

            // ---- issue next chunk's attr rows (eN arrived by now) ----
            float4 aN[4];
            if (more) {
#pragma unroll
                for (int p = 0; p < 4; ++p)
                    aN[p] = a4[(size_t)eN[p] * NF4 + jp];
            }

            // ---- epilogue: +x, ReLU, ds_add into Acc[node][o] ----
#pragma unroll
            for (int et = 0; et < 4; ++et) {
                int slot = cl + l15 + 16 * et;
                if (slot < s1) {
                    int lo = 0;
#pragma unroll
                    for (int st = 8; st; st >>= 1)
                        if (sstart[lo + st] <= slot) lo += st;
                    float* arow = &Acc[lo][16 * w + 4 * l4];
                    atomicAdd(arow + 0, fmaxf(acc[et][0] + xV[et].x, 0.f));
                    atomicAdd(arow + 1, fmaxf(acc[et][1] + xV[et].y, 0.f));
                    atomicAdd(arow + 2, fmaxf(acc[et][2] + xV[et].z, 0.f));
                    atomicAdd(arow + 3, fmaxf(acc[et][3] + xV[et].w, 0.f));
                }
            }

            // B2: all waves done reading Bt before next overwrite
            asm volatile("s_barrier" ::: "memory");

            if (more) {
#pragma unroll
                for (int p = 0; p < 4; ++p) aV[p] = aN[p];
#pragma unroll
                for (int et = 0; et < 4; ++et) sV[et] = sN[et];
            }
        }
    }

    __syncthreads();  // drain all ds_add before reading Acc

    // ---- write h = aggr + (1+eps)*x ----
    const float ep = 1.0f + *epsp;
#pragma unroll
    for (int r = 0; r < 4; ++r) {
        int item = t + THREADS * r;
        int n = item / NF, f = item % NF;
        h[(size_t)(n0 + n) * NF + f] =
            fmaf(ep, x[(size_t)(n0 + n) * NF + f], Acc[n][f]);
    }
}

// ---------------------------------------------------------------------------
// Node MLP: out = relu(h @ W1^T + b1) @ W2^T + b2   (fp32 VALU)
// ---------------------------------------------------------------------------
#define LDS_STRIDE 65
__global__ __launch_bounds__(THREADS) void node_kernel(
    const float* __restrict__ h,
    const float* __restrict__ W1t, const float* __restrict__ b1,
    const float* __restrict__ W2t, const float* __restrict__ b2,
    float* __restrict__ out) {
    __shared__ float Ht[NF][LDS_STRIDE];
    __shared__ float H1t[NF][LDS_STRIDE];

    const int t = threadIdx.x;
    const int n0 = blockIdx.x * 64;

    const float4* h4 = reinterpret_cast<const float4*>(h);
#pragma unroll
    for (int j = 0; j < 4; ++j) {
        int f4 = t + THREADS * j;
        int n = f4 / NF4, k4 = f4 % NF4;
        float4 v = make_float4(0.f, 0.f, 0.f, 0.f);
        if (n0 + n < NNODES) v = h4[(size_t)(n0 + n) * NF4 + k4];
        Ht[4 * k4 + 0][n] = v.x;
        Ht[4 * k4 + 1][n] = v.y;
        Ht[4 * k4 + 2][n] = v.z;
        Ht[4 * k4 + 3][n] = v.w;
    }
    __syncthreads();

    const int lane = t & 63;
    const int wv = __builtin_amdgcn_readfirstlane(t >> 6);
    const int ob4 = wv * 4;
    const float4* W1t4 = reinterpret_cast<const float4*>(W1t);
    const float4* W2t4 = reinterpret_cast<const float4*>(W2t);
    const float4* b14 = reinterpret_cast<const float4*>(b1);
    const float4* b24 = reinterpret_cast<const float4*>(b2);

    float acc[16];
#pragma unroll
    for (int j = 0; j < 4; ++j) {
        float4 b = b14[ob4 + j];
        acc[4 * j + 0] = b.x; acc[4 * j + 1] = b.y;
        acc[4 * j + 2] = b.z; acc[4 * j + 3] = b.w;
    }
#pragma unroll 8
    for (int k = 0; k < NF; ++k) {
        float a = Ht[k][lane];
#pragma unroll
        for (int j = 0; j < 4; ++j) {
            float4 w = W1t4[k * NF4 + ob4 + j];
            acc[4 * j + 0] = fmaf(a, w.x, acc[4 * j + 0]);
            acc[4 * j + 1] = fmaf(a, w.y, acc[4 * j + 1]);
            acc[4 * j + 2] = fmaf(a, w.z, acc[4 * j + 2]);
            acc[4 * j + 3] = fmaf(a, w.w, acc[4 * j + 3]);
        }
    }
#pragma unroll
    for (int j = 0; j < 16; ++j)
        H1t[wv * 16 + j][lane] = fmaxf(acc[j], 0.0f);
    __syncthreads();

    float acc2[16];
#pragma unroll
    for (int j = 0; j < 4; ++j) {
        float4 b = b24[ob4 + j];
        acc2[4 * j + 0] = b.x; acc2[4 * j + 1] = b.y;
        acc2[4 * j + 2] = b.z; acc2[4 * j + 3] = b.w;
    }
#pragma unroll 8
    for (int k = 0; k < NF; ++k) {
        float a = H1t[k][lane];
#pragma unroll
        for (int j = 0; j < 4; ++j) {
            float4 w = W2t4[k * NF4 + ob4 + j];
            acc2[4 * j + 0] = fmaf(a, w.x, acc2[4 * j + 0]);
            acc2[4 * j + 1] = fmaf(a, w.y, acc2[4 * j + 1]);
            acc2[4 * j + 2] = fmaf(a, w.z, acc2[4 * j + 2]);
            acc2[4 * j + 3] = fmaf(a, w.w, acc2[4 * j + 3]);
        }
    }

    const int n = n0 + lane;
    if (n < NNODES) {
        float4* o4 = reinterpret_cast<float4*>(out) + (size_t)n * NF4;
#pragma unroll
        for (int j = 0; j < 4; ++j)
            o4[ob4 + j] = make_float4(acc2[4 * j + 0], acc2[4 * j + 1],
                                      acc2[4 * j + 2], acc2[4 * j + 3]);
    }
}

// ---------------------------------------------------------------------------
extern "C" void kernel_launch(void* const* d_in, const int* in_sizes, int n_in,
                              void* d_out, int out_size, void* d_ws, size_t ws_size,
                              hipStream_t stream) {
    const float* x   = (const float*)d_in[0];
    const int*   ei  = (const int*)d_in[1];
    const float* ea  = (const float*)d_in[2];
    const float* We  = (const float*)d_in[3];
    const float* be  = (const float*)d_in[4];
    const float* eps = (const float*)d_in[5];
    const float* W1  = (const float*)d_in[6];
    const float* b1  = (const float*)d_in[7];
    const float* W2  = (const float*)d_in[8];
    const float* b2  = (const float*)d_in[9];
    float* out = (float*)d_out;

    // ws layout
    float* h    = (float*)d_ws;                         // 50000*96 f (19.2 MB)
    float* W1t  = h + (size_t)NNODES * NF;              // 96*96 f
    float* W2t  = W1t + NF * NF;                        // 96*96 f
    unsigned short* Wb = (unsigned short*)(W2t + NF * NF);  // 96*96 bf16
    int* deg    = (int*)(Wb + NF * NF);                 // 50000
    int* start  = deg + NNODES;                         // 50001
    int* cursor = start + NNODES + 1;                   // 50000
    int* eidx   = cursor + NNODES;                      // 800000
    int* srcs   = eidx + NEDGES;                        // 800000
    int* bsum   = srcs + NEDGES;                        // 256
    int* bstart = bsum + 256;                           // 256

    hipMemsetAsync(deg, 0, NNODES * sizeof(int), stream);
    prep_hist<<<3 + (NEDGES + 255) / 256, 256, 0, stream>>>(We, W1, W2, Wb, W1t,
                                                            W2t, ei, deg);
    scan_partial<<<SCAN_BLOCKS, 256, 0, stream>>>(deg, bsum);
    scan_bsum<<<1, 256, 0, stream>>>(bsum, bstart);
    scan_write<<<SCAN_BLOCKS, 256, 0, stream>>>(deg, bstart, start, cursor);
    fill_kernel<<<(NEDGES + 255) / 256, 256, 0, stream>>>(ei, cursor, eidx, srcs);
    fused_edge_aggr<<<NNODES / NB, THREADS, 0, stream>>>(ea, eidx, srcs, start, x,
                                                         Wb, be, eps, h);
    node_kernel<<<(NNODES + 63) / 64, THREADS, 0, stream>>>(h, W1t, b1, W2t, b2, out);
}

// Round 7
// 331.478 us; speedup vs baseline: 2.2875x; 2.2875x over previous
//
#include <hip/hip_runtime.h>

#define NNODES 50000
#define NEDGES 800000
#define NF 96
#define NF4 24              // float4 per f32 row
#define NBW 8               // nodes per wave (50000 / 8 = 6250 waves)
#define WPB 4               // waves per block (256 threads)
#define ACC_STRIDE 97       // Acc row stride (floats)

typedef short bf16x8 __attribute__((ext_vector_type(8)));
typedef float f32x4 __attribute__((ext_vector_type(4)));

__device__ inline unsigned pk_bf16(float a, float b) {
    union { __bf16 h[2]; unsigned u; } q;
    q.h[0] = (__bf16)a; q.h[1] = (__bf16)b;
    return q.u;
}
__device__ inline unsigned short bf16_1(float a) {
    union { __bf16 h; unsigned short u; } q;
    q.h = (__bf16)a;
    return q.u;
}
__device__ inline bf16x8 cvt8(float4 a, float4 b) {
    union { unsigned u[4]; bf16x8 v; } q;
    q.u[0] = pk_bf16(a.x, a.y); q.u[1] = pk_bf16(a.z, a.w);
    q.u[2] = pk_bf16(b.x, b.y); q.u[3] = pk_bf16(b.z, b.w);
    return q.v;
}

// ---------------------------------------------------------------------------
// prep: b0 = Wpack (pre-packed MFMA B-fragments of W_edge), b1/b2 = W1^T/W2^T,
// rest = dst histogram.
// Wpack[((ot*3+kb)*64 + lane)*8 + j] = bf16(We[(ot*16+(lane&15))*96 + kb*32+(lane>>4)*8+j])
// ---------------------------------------------------------------------------
__global__ __launch_bounds__(256) void prep_hist(
    const float* __restrict__ We, const float* __restrict__ W1,
    const float* __restrict__ W2, unsigned short* __restrict__ Wpack,
    float* __restrict__ W1t, float* __restrict__ W2t,
    const int* __restrict__ ei, int* __restrict__ deg) {
    int b = blockIdx.x;
    if (b == 0) {
        for (int i = threadIdx.x; i < 18 * 64 * 8; i += blockDim.x) {
            int f = i >> 9;          // 0..17
            int rem = i & 511;
            int l = rem >> 3, j = rem & 7;
            int ot = f / 3, kb = f % 3;
            int o = ot * 16 + (l & 15);
            int k = kb * 32 + ((l >> 4) << 3) + j;
            Wpack[i] = bf16_1(We[o * NF + k]);
        }
    } else if (b == 1) {
        for (int i = threadIdx.x; i < NF * NF; i += blockDim.x)
            W1t[(i % NF) * NF + i / NF] = W1[i];
    } else if (b == 2) {
        for (int i = threadIdx.x; i < NF * NF; i += blockDim.x)
            W2t[(i % NF) * NF + i / NF] = W2[i];
    } else {
        int e = (b - 3) * 256 + threadIdx.x;
        if (e < NEDGES) atomicAdd(&deg[ei[NEDGES + e]], 1);
    }
}

// ---------------------------------------------------------------------------
// 3-phase multi-block scan + slot fill (int atomics only)
// ---------------------------------------------------------------------------
#define SCAN_BLOCKS 196  // ceil(50000 / 256)

__global__ __launch_bounds__(256) void scan_partial(const int* __restrict__ deg,
                                                    int* __restrict__ bsum) {
    __shared__ int red[256];
    int t = threadIdx.x;
    int i = blockIdx.x * 256 + t;
    red[t] = (i < NNODES) ? deg[i] : 0;
    __syncthreads();
    for (int off = 128; off; off >>= 1) {
        if (t < off) red[t] += red[t + off];
        __syncthreads();
    }
    if (t == 0) bsum[blockIdx.x] = red[0];
}

__global__ __launch_bounds__(256) void scan_bsum(const int* __restrict__ bsum,
                                                 int* __restrict__ bstart) {
    __shared__ int s[256];
    int t = threadIdx.x;
    s[t] = (t < SCAN_BLOCKS) ? bsum[t] : 0;
    __syncthreads();
    for (int off = 1; off < 256; off <<= 1) {
        int v = (t >= off) ? s[t - off] : 0;
        __syncthreads();
        s[t] += v;
        __syncthreads();
    }
    bstart[t] = (t == 0) ? 0 : s[t - 1];  // exclusive
}

__global__ __launch_bounds__(256) void scan_write(const int* __restrict__ deg,
                                                  const int* __restrict__ bstart,
                                                  int* __restrict__ start,
                                                  int* __restrict__ cursor) {
    __shared__ int s[256];
    int t = threadIdx.x;
    int i = blockIdx.x * 256 + t;
    int d = (i < NNODES) ? deg[i] : 0;
    s[t] = d;
    __syncthreads();
    for (int off = 1; off < 256; off <<= 1) {
        int v = (t >= off) ? s[t - off] : 0;
        __syncthreads();
        s[t] += v;
        __syncthreads();
    }
    int excl = ((t == 0) ? 0 : s[t - 1]) + bstart[blockIdx.x];
    if (i < NNODES) {
        start[i] = excl;
        cursor[i] = excl;
        if (i == NNODES - 1) start[NNODES] = excl + d;
    }
}

// fill: eidx[p]=edge, srcs[p]=src node, snode[p]=dst node
__global__ void fill_kernel(const int* __restrict__ ei, int* __restrict__ cursor,
                            int* __restrict__ eidx, int* __restrict__ srcs,
                            int* __restrict__ snode) {
    int e = blockIdx.x * blockDim.x + threadIdx.x;
    if (e < NEDGES) {
        int d = ei[NEDGES + e];
        int p = atomicAdd(&cursor[d], 1);
        eidx[p] = e;
        srcs[p] = ei[e];
        snode[p] = d;
    }
}

// ---------------------------------------------------------------------------
// Wave-autonomous fused edge-GEMM + segment-sum. Wave owns NBW=8 nodes
// (CSR range [s0,s1)). Per 16-edge tile, NO barriers:
//   - lane gathers its A-frag: attr[eidx[base+l15]][k-span]  (32B x 3 kb)
//   - 18 MFMA: D[e][o] = attr . W^T; B-frags = Wpack via LDS (conflict-free)
//   - D layout: lane holds 4 consecutive edges (e=(lane>>4)*4+r), col o=lane&15
//   - epilogue: relu(D + x[src][o]); in-lane segment-sum over the 4 edges;
//     boundary flushes via ds_add into the wave-PRIVATE Acc (no contention)
// ---------------------------------------------------------------------------
__global__ __launch_bounds__(256) void fused_edge_aggr(
    const float* __restrict__ attr, const int* __restrict__ eidx,
    const int* __restrict__ srcs_g, const int* __restrict__ snode_g,
    const int* __restrict__ start, const float* __restrict__ x,
    const unsigned short* __restrict__ Wpack, const float* __restrict__ be,
    const float* __restrict__ epsp, float* __restrict__ h) {
    __shared__ short Wlds[18 * 64 * 8];             // 18,432 B
    __shared__ float Acc[WPB][NBW][ACC_STRIDE];     // 12,416 B

    const int t = threadIdx.x;
    // stage W fragments + zero Acc (only block-wide sync in the kernel)
    {
        const uint4* wsrc = reinterpret_cast<const uint4*>(Wpack);
        uint4* wdst = reinterpret_cast<uint4*>(Wlds);
        for (int i = t; i < 18 * 64 * 8 / 8; i += 256) wdst[i] = wsrc[i];
        float* accf = &Acc[0][0][0];
        for (int i = t; i < WPB * NBW * ACC_STRIDE; i += 256) accf[i] = 0.f;
    }
    __syncthreads();

    const int w = t >> 6;
    const int lane = t & 63;
    const int l15 = lane & 15, l4 = lane >> 4;
    const int n0w = (blockIdx.x * WPB + w) * NBW;
    if (n0w >= NNODES) return;
    const int s0 = start[n0w], s1 = start[n0w + NBW];
    float* AccW = &Acc[w][0][0];

    float bias[6];
#pragma unroll
    for (int ot = 0; ot < 6; ++ot) bias[ot] = be[ot * 16 + l15];

    const float4* a4 = reinterpret_cast<const float4*>(attr);

    for (int base = s0; base < s1; base += 16) {
        // ---- A-side chain first (longest latency) ----
        int sl = base + l15;
        int ev = eidx[sl < s1 ? sl : s1 - 1];
        const float4* arow = a4 + (size_t)ev * NF4 + l4 * 2;
        float4 r0 = arow[0], r1 = arow[1];      // kb=0
        float4 r2 = arow[8], r3 = arow[9];      // kb=1
        float4 r4 = arow[16], r5 = arow[17];    // kb=2

        // ---- indices for this lane's 4 edges (raw loads + mask) ----
        const int e0 = base + l4 * 4;
        int mraw[4], svraw[4];
#pragma unroll
        for (int r = 0; r < 4; ++r) {
            mraw[r] = snode_g[e0 + r];   // padded arrays: safe past s1
            svraw[r] = srcs_g[e0 + r];
        }
        int m[4], sv[4];
#pragma unroll
        for (int r = 0; r < 4; ++r) {
            bool val = (e0 + r) < s1;
            m[r] = val ? (mraw[r] - n0w) : -1;
            sv[r] = val ? svraw[r] : 0;
        }

        // ---- x gathers: xe[r][ot] = x[src(e_r)][ot*16 + l15] ----
        float xe[4][6];
#pragma unroll
        for (int r = 0; r < 4; ++r) {
            const float* xr = x + (size_t)sv[r] * NF + l15;
#pragma unroll
            for (int ot = 0; ot < 6; ++ot) xe[r][ot] = xr[ot * 16];
        }

        // ---- convert A-frags ----
        bf16x8 af[3];
        af[0] = cvt8(r0, r1);
        af[1] = cvt8(r2, r3);
        af[2] = cvt8(r4, r5);

        // ---- 18 MFMA: D[e][o] ----
        f32x4 acc[6];
#pragma unroll
        for (int ot = 0; ot < 6; ++ot) {
            f32x4 c = {bias[ot], bias[ot], bias[ot], bias[ot]};
#pragma unroll
            for (int kb = 0; kb < 3; ++kb) {
                bf16x8 bf = *reinterpret_cast<const bf16x8*>(
                    &Wlds[((ot * 3 + kb) * 64 + lane) * 8]);
                c = __builtin_amdgcn_mfma_f32_16x16x32_bf16(af[kb], bf, c, 0, 0, 0);
            }
            acc[ot] = c;
        }

        // ---- epilogue: relu + in-lane segmented reduce + ds_add flushes ----
        const bool c1 = (m[1] == m[0]);
        const bool c2 = (m[2] == m[1]);
        const bool c3 = (m[3] == m[2]);
#pragma unroll
        for (int ot = 0; ot < 6; ++ot) {
            const int o = ot * 16 + l15;
            float v0 = fmaxf(acc[ot][0] + xe[0][ot], 0.f);
            float v1 = fmaxf(acc[ot][1] + xe[1][ot], 0.f);
            float v2 = fmaxf(acc[ot][2] + xe[2][ot], 0.f);
            float v3 = fmaxf(acc[ot][3] + xe[3][ot], 0.f);
            float run = v0;
            if (!c1) {
                if (m[0] >= 0) atomicAdd(&AccW[m[0] * ACC_STRIDE + o], run);
                run = 0.f;
            }
            run += v1;
            if (!c2) {
                if (m[1] >= 0) atomicAdd(&AccW[m[1] * ACC_STRIDE + o], run);
                run = 0.f;
            }
            run += v2;
            if (!c3) {
                if (m[2] >= 0) atomicAdd(&AccW[m[2] * ACC_STRIDE + o], run);
                run = 0.f;
            }
            run += v3;
            if (m[3] >= 0) atomicAdd(&AccW[m[3] * ACC_STRIDE + o], run);
        }
    }

    // ---- drain this wave's ds_adds, then write h (wave-private; no barrier) ----
    asm volatile("s_waitcnt lgkmcnt(0)" ::: "memory");
    __builtin_amdgcn_sched_barrier(0);
    const float ep = 1.0f + *epsp;
#pragma unroll
    for (int i = 0; i < NBW * NF / 64; ++i) {  // 12
        int item = lane + 64 * i;
        int n = item / NF, f = item % NF;
        float a = AccW[n * ACC_STRIDE + f];
        size_t g = (size_t)(n0w + n) * NF + f;
        h[g] = fmaf(ep, x[g], a);
    }
}

// ---------------------------------------------------------------------------
// Node MLP: out = relu(h @ W1^T + b1) @ W2^T + b2   (fp32 VALU)
// ---------------------------------------------------------------------------
#define MLP_THREADS 384
#define LDS_STRIDE 65
__global__ __launch_bounds__(MLP_THREADS) void node_kernel(
    const float* __restrict__ h,
    const float* __restrict__ W1t, const float* __restrict__ b1,
    const float* __restrict__ W2t, const float* __restrict__ b2,
    float* __restrict__ out) {
    __shared__ float Ht[NF][LDS_STRIDE];
    __shared__ float H1t[NF][LDS_STRIDE];

    const int t = threadIdx.x;
    const int n0 = blockIdx.x * 64;

    const float4* h4 = reinterpret_cast<const float4*>(h);
#pragma unroll
    for (int j = 0; j < 4; ++j) {
        int f4 = t + MLP_THREADS * j;
        int n = f4 / NF4, k4 = f4 % NF4;
        float4 v = make_float4(0.f, 0.f, 0.f, 0.f);
        if (n0 + n < NNODES) v = h4[(size_t)(n0 + n) * NF4 + k4];
        Ht[4 * k4 + 0][n] = v.x;
        Ht[4 * k4 + 1][n] = v.y;
        Ht[4 * k4 + 2][n] = v.z;
        Ht[4 * k4 + 3][n] = v.w;
    }
    __syncthreads();

    const int lane = t & 63;
    const int wv = __builtin_amdgcn_readfirstlane(t >> 6);
    const int ob4 = wv * 4;
    const float4* W1t4 = reinterpret_cast<const float4*>(W1t);
    const float4* W2t4 = reinterpret_cast<const float4*>(W2t);
    const float4* b14 = reinterpret_cast<const float4*>(b1);
    const float4* b24 = reinterpret_cast<const float4*>(b2);

    float acc[16];
#pragma unroll
    for (int j = 0; j < 4; ++j) {
        float4 b = b14[ob4 + j];
        acc[4 * j + 0] = b.x; acc[4 * j + 1] = b.y;
        acc[4 * j + 2] = b.z; acc[4 * j + 3] = b.w;
    }
#pragma unroll 8
    for (int k = 0; k < NF; ++k) {
        float a = Ht[k][lane];
#pragma unroll
        for (int j = 0; j < 4; ++j) {
            float4 w = W1t4[k * NF4 + ob4 + j];
            acc[4 * j + 0] = fmaf(a, w.x, acc[4 * j + 0]);
            acc[4 * j + 1] = fmaf(a, w.y, acc[4 * j + 1]);
            acc[4 * j + 2] = fmaf(a, w.z, acc[4 * j + 2]);
            acc[4 * j + 3] = fmaf(a, w.w, acc[4 * j + 3]);
        }
    }
#pragma unroll
    for (int j = 0; j < 16; ++j)
        H1t[wv * 16 + j][lane] = fmaxf(acc[j], 0.0f);
    __syncthreads();

    float acc2[16];
#pragma unroll
    for (int j = 0; j < 4; ++j) {
        float4 b = b24[ob4 + j];
        acc2[4 * j + 0] = b.x; acc2[4 * j + 1] = b.y;
        acc2[4 * j + 2] = b.z; acc2[4 * j + 3] = b.w;
    }
#pragma unroll 8
    for (int k = 0; k < NF; ++k) {
        float a = H1t[k][lane];
#pragma unroll
        for (int j = 0; j < 4; ++j) {
            float4 w = W2t4[k * NF4 + ob4 + j];
            acc2[4 * j + 0] = fmaf(a, w.x, acc2[4 * j + 0]);
            acc2[4 * j + 1] = fmaf(a, w.y, acc2[4 * j + 1]);
            acc2[4 * j + 2] = fmaf(a, w.z, acc2[4 * j + 2]);
            acc2[4 * j + 3] = fmaf(a, w.w, acc2[4 * j + 3]);
        }
    }

    const int n = n0 + lane;
    if (n < NNODES) {
        float4* o4 = reinterpret_cast<float4*>(out) + (size_t)n * NF4;
#pragma unroll
        for (int j = 0; j < 4; ++j)
            o4[ob4 + j] = make_float4(acc2[4 * j + 0], acc2[4 * j + 1],
                                      acc2[4 * j + 2], acc2[4 * j + 3]);
    }
}

// ---------------------------------------------------------------------------
extern "C" void kernel_launch(void* const* d_in, const int* in_sizes, int n_in,
                              void* d_out, int out_size, void* d_ws, size_t ws_size,
                              hipStream_t stream) {
    const float* x   = (const float*)d_in[0];
    const int*   ei  = (const int*)d_in[1];
    const float* ea  = (const float*)d_in[2];
    const float* We  = (const float*)d_in[3];
    const float* be  = (const float*)d_in[4];
    const float* eps = (const float*)d_in[5];
    const float* W1  = (const float*)d_in[6];
    const float* b1  = (const float*)d_in[7];
    const float* W2  = (const float*)d_in[8];
    const float* b2  = (const float*)d_in[9];
    float* out = (float*)d_out;

    // ws layout
    float* h    = (float*)d_ws;                          // 50000*96 f (19.2 MB)
    float* W1t  = h + (size_t)NNODES * NF;               // 96*96 f
    float* W2t  = W1t + NF * NF;                         // 96*96 f
    unsigned short* Wpack = (unsigned short*)(W2t + NF * NF);  // 18*64*8 bf16
    int* deg    = (int*)(Wpack + 18 * 64 * 8);           // 50000
    int* start  = deg + NNODES;                          // 50001
    int* cursor = start + NNODES + 1;                    // 50000
    int* eidx   = cursor + NNODES;                       // 800000 (+pad)
    int* srcs   = eidx + NEDGES + 16;                    // 800000 (+pad)
    int* snode  = srcs + NEDGES + 16;                    // 800000 (+pad)
    int* bsum   = snode + NEDGES + 16;                   // 256
    int* bstart = bsum + 256;                            // 256

    hipMemsetAsync(deg, 0, NNODES * sizeof(int), stream);
    prep_hist<<<3 + (NEDGES + 255) / 256, 256, 0, stream>>>(We, W1, W2, Wpack,
                                                            W1t, W2t, ei, deg);
    scan_partial<<<SCAN_BLOCKS, 256, 0, stream>>>(deg, bsum);
    scan_bsum<<<1, 256, 0, stream>>>(bsum, bstart);
    scan_write<<<SCAN_BLOCKS, 256, 0, stream>>>(deg, bstart, start, cursor);
    fill_kernel<<<(NEDGES + 255) / 256, 256, 0, stream>>>(ei, cursor, eidx, srcs,
                                                          snode);
    int nwaves = (NNODES + NBW - 1) / NBW;               // 6250
    int nblocks = (nwaves + WPB - 1) / WPB;              // 1563
    fused_edge_aggr<<<nblocks, 256, 0, stream>>>(ea, eidx, srcs, snode, start, x,
                                                 Wpack, be, eps, h);
    node_kernel<<<(NNODES + 63) / 64, MLP_THREADS, 0, stream>>>(h, W1t, b1, W2t,
                                                                b2, out);
}